// Round 9
// baseline (154.673 us; speedup 1.0000x reference)
//
#include <hip/hip_runtime.h>
#include <hip/hip_bf16.h>

// Mex forward: B=64,C=64,H=W=64, BLK=(64,3,3), STR=(64,2,2), PAD=(0,1,1),
// NI=256, EPS=1, mean mode. OH=OW=32, K=576, out (64,256,32,32) fp32.
//
// y[n][i] = log( sum_k exp(P[n][k] + O[i][k]) ) - log(576)
// Shift-invariant -> no max pass. Zero-padded entries -> exp(0)=1.
//
// v9: depth-4 persistent pipeline. Grid 256 x 512thr, 1 block/CU, LDS =
//     4 x 40 KB tile buffers = 160 KiB exactly. Each block owns 4 adjacent
//     oh-pair tiles of one image. Steady-state iteration:
//       issue loads(t+2) -> [ kloop(t) || epi(t-1) || exp+write(t+1) ] -> bar
//     so HBM issue is spread over the whole kernel instead of the chip-wide
//     read-burst/compute/write-burst lockstep that capped v5/v8 at 3.0 of
//     6.3 TB/s (traffic is at floor; rate was the loss).
//     Tile adjacency: tile t's hl0 row == tile t-1's hl4 row, still in LDS
//     -> stage only 4 new rows/tile (kloop reads hl0 from the prev buffer);
//     read traffic -15%. Staging keeps v5's full-chunk bf16x8 writes (v8's
//     half-chunk bf16x4 writes doubled LDS bank conflicts).
// v8-lesson: more waves/CU alone does nothing (16w = 64.5us vs 8w = 61.5us).
// v7-lesson: NT stores stall the store queue; WRITE_SIZE ~55MB over output
//     is harness memset drain (3 store patterns, same number) - closed.
// v3: left pad via in-register ones-select; Bt laid out for coalesced 1 KB
//     wave loads; K-loop fully unrolled; distance-2 B prefetch.

typedef __bf16 bf16x8 __attribute__((ext_vector_type(8)));
typedef float  f32x4  __attribute__((ext_vector_type(4)));

// ---- BtL[(ks*16 + g)*64 + q*16 + t16][j] = bf16(exp(off[i][c][p]))
// where g = inst>>4, c = c8*8+j, ks = 2*p + (c8>>2), q = c8&3.
__global__ void mex_prep_b(const float* __restrict__ off, __bf16* __restrict__ Bt) {
    const int i = blockIdx.x * 4 + (threadIdx.x >> 6);  // instance
    const int c = threadIdx.x & 63;                     // channel
    const int c8 = c >> 3, j = c & 7;
    const int g  = i >> 4, t16 = i & 15;
    const int q  = c8 & 3;
    const float* oi = off + i * 576;
    #pragma unroll
    for (int p = 0; p < 9; ++p) {
        float v = oi[c * 9 + p];                        // original k = c*9 + p
        const int ks    = p * 2 + (c8 >> 2);
        const int chunk = (ks * 16 + g) * 64 + q * 16 + t16;
        Bt[chunk * 8 + j] = (__bf16)__expf(v);
    }
}

// ---- main fused kernel ----------------------------------------------------
__global__ __launch_bounds__(512, 2) void mex_main(
        const float* __restrict__ x,
        const __bf16* __restrict__ Bt,
        float* __restrict__ out) {
    // 4 buffers: [buf 0..3][hl 0..4][w 0..63][chunk 0..7] bf16x8 = 163840 B
    __shared__ bf16x8 lds8[4 * 2560];

    const int bid = blockIdx.x;      // 0..255
    // XCD-chunked swizzle (256 % 8 == 0 -> bijective): 4 j-blocks of the
    // same image b land on one XCD's L2 (shared halo rows + shared Bt).
    const int wid = ((bid & 7) << 5) | (bid >> 3);
    const int b   = wid >> 2;
    const int ohB = (wid & 3) << 3;  // tiles: oh0 = ohB, ohB+2, ohB+4, ohB+6
    const int tid  = threadIdx.x;    // 0..511
    const int wv   = tid >> 6;       // 0..7
    const int lane = tid & 63;

    bf16x8 one8;
    #pragma unroll
    for (int j = 0; j < 8; ++j) one8[j] = (__bf16)1.0f;

    // staging geometry: thread t -> w-pair wp (w0 = 2*wp), c-chunk c8 (0..7),
    // row-group hgrp (0/1). Swizzled slot c8 ^ (wp&7) == c8 ^ ((w>>1)&7).
    const int wp   = tid & 31;
    const int w0   = wp << 1;
    const int c8   = (tid >> 5) & 7;
    const int hgrp = tid >> 8;       // 0: rows 0..2(pro)/1..2; 1: rows 3..4
    const int c8p  = c8 ^ (wp & 7);
    const float* xb = x + ((size_t)b << 18) + w0;   // + c*4096 + h*64

    // ---- top pad: tile0 hl0 = ones when ohB == 0 (h_global = -1) ---------
    if (ohB == 0) lds8[tid] = one8;  // row hl0 = 512 chunks

    // ---- prologue: stage tile0 (5 rows) directly -------------------------
    #pragma unroll
    for (int rr = 0; rr < 3; ++rr) {
        const int hl = hgrp * 3 + rr;               // 0,1,2 / 3,4,(5)
        if (hl < 5) {
            const int hg = 2 * ohB - 1 + hl;
            if (hg >= 0) {                          // only ohB==0, hl==0 skips
                const float* xp = xb + (hg << 6);
                float2 v[8];
                #pragma unroll
                for (int k = 0; k < 8; ++k)
                    v[k] = *(const float2*)(xp + (((c8 << 3) + k) << 12));
                bf16x8 ca, cb;
                #pragma unroll
                for (int k = 0; k < 8; ++k) {
                    ca[k] = (__bf16)__expf(v[k].x);
                    cb[k] = (__bf16)__expf(v[k].y);
                }
                bf16x8* dst = lds8 + hl * 512 + w0 * 8 + c8p;
                dst[0] = ca;        // w = w0
                dst[8] = cb;        // w = w0+1 (same swizzle slot)
            }
        }
    }

    // prefetch-issue of a tile's 4 NEW rows (hl 1..4), 2 rows per hgrp
    float2 va[16], vb[16];
    auto issue4 = [&](int oh0, float2 (&vv)[16]) {
        const float* xp = xb + (((oh0 << 1) + (hgrp << 1)) << 6); // hg = 2*oh0+2*hgrp+rr
        #pragma unroll
        for (int rr = 0; rr < 2; ++rr)
            #pragma unroll
            for (int k = 0; k < 8; ++k)
                vv[rr * 8 + k] =
                    *(const float2*)(xp + (rr << 6) + (((c8 << 3) + k) << 12));
    };
    // exp + swizzled LDS write of a prefetched tile (rows hl 1..4)
    auto write4 = [&](bf16x8* buf, float2 (&vv)[16]) {
        #pragma unroll
        for (int rr = 0; rr < 2; ++rr) {
            const int hl = 1 + (hgrp << 1) + rr;
            bf16x8 ca, cb;
            #pragma unroll
            for (int k = 0; k < 8; ++k) {
                ca[k] = (__bf16)__expf(vv[rr * 8 + k].x);
                cb[k] = (__bf16)__expf(vv[rr * 8 + k].y);
            }
            bf16x8* dst = buf + hl * 512 + w0 * 8 + c8p;
            dst[0] = ca;
            dst[8] = cb;
        }
    };

    // ---- B fragments (wave owns N=32 slice; distance-2 rotation) ---------
    const bf16x8* __restrict__ Btv = (const bf16x8*)Bt;
    const int g0 = wv << 1;
    bf16x8 b0[2], b1[2];
    auto bload = [&]() {
        #pragma unroll
        for (int nt = 0; nt < 2; ++nt) {
            b0[nt] = Btv[(g0 + nt) * 64 + lane];         // ks = 0
            b1[nt] = Btv[(16 + g0 + nt) * 64 + lane];    // ks = 1
        }
    };

    const int t16 = tid & 15;
    const int q   = (tid >> 4) & 3;
    int hb[4], wo2[4];
    #pragma unroll
    for (int mt = 0; mt < 4; ++mt) {
        const int m = mt * 16 + t16;
        wo2[mt] = (m & 31) << 1;      // 2*ow
        hb[mt]  = (m >> 5) << 7;      // (2*ohl) * 64
    }
    const float lK = 6.356107660695891f;   // log(576)

    // K-loop: Lc = this tile's buffer (hl1..4 valid); L0 = the hl0 ROW
    // (tile0: own row 0; tile t>0: prev buffer + 4*512).
    auto kloop = [&](const bf16x8* __restrict__ Lc,
                     const bf16x8* __restrict__ L0, f32x4 (&acc)[4][2]) {
        #pragma unroll
        for (int mt = 0; mt < 4; ++mt)
            #pragma unroll
            for (int nt = 0; nt < 2; ++nt) acc[mt][nt] = (f32x4)(0.0f);
        #pragma unroll
        for (int ks = 0; ks < 18; ++ks) {
            const int p  = ks >> 1;
            const int fh = (p * 11) >> 5;          // p/3 (const after unroll)
            const int fw = p - fh * 3;
            const int ccq = ((ks & 1) << 2) + q;
            bf16x8 a[4];
            #pragma unroll
            for (int mt = 0; mt < 4; ++mt) {
                const int wc  = wo2[mt] + fw - 1;  // w_global, -1..63
                const int pad = wc < 0;            // only fw==0 & ow==0
                const int wcl = pad ? 0 : wc;
                // hl = 2*ohl + fh; hl==0 only for mt<2 && fh==0 -> L0 row
                const bf16x8* base = (mt < 2 && fh == 0)
                    ? L0 : (Lc + (hb[mt] + fh * 64) * 8);
                bf16x8 vv = base[wcl * 8 + (ccq ^ ((wcl >> 1) & 7))];
                a[mt] = pad ? one8 : vv;
            }
            bf16x8 b2[2];
            if (ks < 16) {
                #pragma unroll
                for (int nt = 0; nt < 2; ++nt)
                    b2[nt] = Btv[((ks + 2) * 16 + g0 + nt) * 64 + lane];
            }
            #pragma unroll
            for (int mt = 0; mt < 4; ++mt)
                #pragma unroll
                for (int nt = 0; nt < 2; ++nt)
                    acc[mt][nt] = __builtin_amdgcn_mfma_f32_16x16x32_bf16(
                        a[mt], b0[nt], acc[mt][nt], 0, 0, 0);
            #pragma unroll
            for (int nt = 0; nt < 2; ++nt) { b0[nt] = b1[nt]; b1[nt] = b2[nt]; }
        }
    };

    // direct-store epilogue: y = log(S) - log(576)
    auto epi = [&](f32x4 (&acc)[4][2], int oh0) {
        #pragma unroll
        for (int mt = 0; mt < 4; ++mt) {
            const int m   = mt * 16 + (q << 2);    // C/D: row = q*4 + reg
            const int ohl = m >> 5;
            const int owi = m & 31;
            const int orow = (oh0 + ohl) * 32 + owi;
            #pragma unroll
            for (int nt = 0; nt < 2; ++nt) {
                const int inst = wv * 32 + nt * 16 + t16;  // C/D: col = t16
                f32x4 r;
                #pragma unroll
                for (int j = 0; j < 4; ++j)
                    r[j] = __logf(acc[mt][nt][j]) - lK;
                *(f32x4*)(out + (((size_t)b * 256 + inst) * 1024 + orow)) = r;
            }
        }
    };

    f32x4 accA[4][2], accB[4][2];

    issue4(ohB + 2, va);         // tile1 rows -> regs
    bload();
    __syncthreads();             // buf0 ready

    // t = 0
    issue4(ohB + 4, vb);         // tile2
    kloop(lds8, lds8, accA);     // tile0: own hl0 row
    write4(lds8 + 2560, va);     // buf1 (hl1..4)
    bload();
    __syncthreads();

    // t = 1
    issue4(ohB + 6, va);         // tile3
    kloop(lds8 + 2560, lds8 + 4 * 512, accB);
    epi(accA, ohB);              // overlaps kloop/write in this region
    write4(lds8 + 2 * 2560, vb); // buf2
    bload();
    __syncthreads();

    // t = 2
    kloop(lds8 + 2 * 2560, lds8 + 2560 + 4 * 512, accA);
    epi(accB, ohB + 2);
    write4(lds8 + 3 * 2560, va); // buf3
    bload();
    __syncthreads();

    // t = 3
    kloop(lds8 + 3 * 2560, lds8 + 2 * 2560 + 4 * 512, accB);
    epi(accA, ohB + 4);
    epi(accB, ohB + 6);
}

extern "C" void kernel_launch(void* const* d_in, const int* in_sizes, int n_in,
                              void* d_out, int out_size, void* d_ws, size_t ws_size,
                              hipStream_t stream) {
    const float* x   = (const float*)d_in[0];   // (64,64,64,64) fp32
    const float* off = (const float*)d_in[1];   // (1,256,64,3,3) fp32
    float* out = (float*)d_out;                 // (64,256,32,32) fp32
    __bf16* Bt = (__bf16*)d_ws;                 // 294912 B

    mex_prep_b<<<64, 256, 0, stream>>>(off, Bt);
    mex_main<<<256, 512, 0, stream>>>(x, Bt, out);
}

// Round 12
// 130.454 us; speedup vs baseline: 1.1857x; 1.1857x over previous
//
#include <hip/hip_runtime.h>
#include <hip/hip_bf16.h>

// Mex forward: B=64,C=64,H=W=64, BLK=(64,3,3), STR=(64,2,2), PAD=(0,1,1),
// NI=256, EPS=1, mean mode. OH=OW=32, K=576, out (64,256,32,32) fp32.
//
// y[n][i] = log( sum_k exp(P[n][k] + O[i][k]) ) - log(576)
// Shift-invariant -> no max pass. Zero-padded entries -> exp(0)=1.
//
// v10b: v10 semantics, de-risked codegen. v10 failed the container twice at
//       the same stage; its only structural novelty was a generic-lambda
//       K-loop (kloop(..., auto&& extra)) instantiated twice around a fully
//       unrolled 18-step body. v10b writes the two K-loops out explicitly
//       with their per-step extras inlined -- same schedule:
//       - tile1's 40 x-loads issue 2-4 per K-step inside kloop0 (was: one
//         ~200-cyc burst -> HBM idle during the ~2000-cyc kloop; chip-wide
//         phase oscillation capped HBM at 3.0/6.3 TB/s);
//       - epi(tile0) fused into kloop1: one f32x4 chunk (4 logf + 1 store)
//         per K-step.
//       Ledger: traffic at floor (v9 FETCH 54MB), more waves null (v8),
//       1 block/CU barriers hurt (v9), NT stores hurt (v7). Memory-issue
//       duty cycle is the remaining lever.
// v5:  2-tile pipeline skeleton (61.5us main): 2 blocks/CU, 256thr,
//      2 barriers; tile1 loads fly under kloop0; epi0 shares kloop1's
//      region. v3: pad via ones-select; Bt coalesced layout; full unroll;
//      distance-2 B prefetch.

typedef __bf16 bf16x8 __attribute__((ext_vector_type(8)));
typedef float  f32x4  __attribute__((ext_vector_type(4)));

// ---- BtL[(ks*16 + wv*4 + nt)*64 + q*16 + t16][j] = bf16(exp(off[i][c][p]))
// where inst i = wv*64+nt*16+t16, c = c8*8+j, ks = 2*p + (c8>>2), q = c8&3.
__global__ void mex_prep_b(const float* __restrict__ off, __bf16* __restrict__ Bt) {
    const int i = blockIdx.x * 4 + (threadIdx.x >> 6);  // instance
    const int c = threadIdx.x & 63;                     // channel
    const int c8 = c >> 3, j = c & 7;
    const int wv = i >> 6, nt = (i >> 4) & 3, t16 = i & 15;
    const int q  = c8 & 3;
    const float* oi = off + i * 576;
    #pragma unroll
    for (int p = 0; p < 9; ++p) {
        float v = oi[c * 9 + p];                        // original k = c*9 + p
        const int ks    = p * 2 + (c8 >> 2);
        const int chunk = (ks * 16 + wv * 4 + nt) * 64 + q * 16 + t16;
        Bt[chunk * 8 + j] = (__bf16)__expf(v);
    }
}

// ---- main fused kernel ----------------------------------------------------
__global__ __launch_bounds__(256, 2) void mex_main(
        const float* __restrict__ x,
        const __bf16* __restrict__ Bt,
        float* __restrict__ out) {
    // two buffers: [buf 0..1][hl 0..4][w 0..63][chunk 0..7] bf16x8 = 81920 B
    __shared__ bf16x8 lds8[2 * 2560];

    const int bid = blockIdx.x;      // 0..511
    // XCD-chunked swizzle (512 % 8 == 0 -> bijective)
    const int wid  = ((bid & 7) << 6) | (bid >> 3);
    const int b    = wid >> 3;
    const int j2   = wid & 7;
    const int oh0a = j2 << 2;        // tile0: oh rows oh0a, oh0a+1
    const int oh0b = oh0a + 2;       // tile1: oh rows oh0b, oh0b+1
    const int tid  = threadIdx.x;
    const int wv   = tid >> 6;
    const int lane = tid & 63;

    bf16x8 one8;
    #pragma unroll
    for (int j = 0; j < 8; ++j) one8[j] = (__bf16)1.0f;

    // ---- top pad for tile0 (h_global = -1), only j2 == 0 -----------------
    if (oh0a == 0) {
        #pragma unroll
        for (int i = 0; i < 2; ++i) lds8[tid + i * 256] = one8;
    }

    // staging geometry: thread t -> w-pair wp (w0 = 2*wp), c-chunk c8.
    // swizzled slot c8 ^ (wp&7) == c8 ^ ((w>>1)&7) for both w0, w0+1.
    const int wp  = tid & 31;
    const int w0  = wp << 1;
    const int c8  = tid >> 5;
    const int c8p = c8 ^ (wp & 7);
    const float* xb = x + ((size_t)b << 18) + w0;   // + c*4096 + h*64

    // ---- stage tile0: x -> exp -> bf16 -> swizzled LDS (chained) ---------
    #pragma unroll
    for (int hl = 0; hl < 5; ++hl) {
        const int hg = 2 * oh0a - 1 + hl;           // -1..31
        if (hg >= 0) {                              // block-uniform
            const float* xp = xb + (hg << 6);
            float2 v[8];
            #pragma unroll
            for (int k = 0; k < 8; ++k)
                v[k] = *(const float2*)(xp + (((c8 << 3) + k) << 12));
            bf16x8 ca, cb;
            #pragma unroll
            for (int k = 0; k < 8; ++k) {
                ca[k] = (__bf16)__expf(v[k].x);
                cb[k] = (__bf16)__expf(v[k].y);
            }
            bf16x8* dst = lds8 + hl * 512 + w0 * 8 + c8p;
            dst[0] = ca;        // w = w0
            dst[8] = cb;        // w = w0+1 (same swizzle slot)
        }
    }

    // tile1 load base: hg = 2*oh0b - 1 + hl = 2*oh0a + 3 + hl (>= 3, no pad)
    float2 v1[40];
    const float* xc = xb + (((oh0b << 1) - 1) << 6) + ((size_t)c8 << 15);

    // ---- first B fragments (distance-2 pipeline) -------------------------
    const bf16x8* __restrict__ Btv = (const bf16x8*)Bt;
    const int wv4 = wv << 2;
    bf16x8 b0[4], b1[4];
    #pragma unroll
    for (int nt = 0; nt < 4; ++nt) {
        b0[nt] = Btv[(wv4 + nt) * 64 + lane];            // ks = 0
        b1[nt] = Btv[(16 + wv4 + nt) * 64 + lane];       // ks = 1
    }

    const int t16 = tid & 15;
    const int q   = (tid >> 4) & 3;
    int hb[4], wo2[4];
    #pragma unroll
    for (int mt = 0; mt < 4; ++mt) {
        const int m = mt * 16 + t16;
        wo2[mt] = (m & 31) << 1;      // 2*ow
        hb[mt]  = (m >> 5) << 7;      // (2*ohl) * 64
    }
    const float lK = 6.356107660695891f;   // log(576)

    f32x4 acc0[4][4], acc1[4][4];
    #pragma unroll
    for (int mt = 0; mt < 4; ++mt)
        #pragma unroll
        for (int nt = 0; nt < 4; ++nt) acc0[mt][nt] = (f32x4)(0.0f);

    __syncthreads();   // B0: buf0 staged

    // ================= kloop0: tile0 MFMA + spread tile1 loads ============
    #pragma unroll
    for (int ks = 0; ks < 18; ++ks) {
        const int p  = ks >> 1;
        const int fh = (p * 11) >> 5;              // p/3 (const after unroll)
        const int fw = p - fh * 3;
        const int ccq = ((ks & 1) << 2) + q;
        bf16x8 a[4];
        #pragma unroll
        for (int mt = 0; mt < 4; ++mt) {
            const int wc  = wo2[mt] + fw - 1;      // w_global, -1..63
            const int pad = wc < 0;                // only fw==0 & ow==0
            const int wcl = pad ? 0 : wc;
            const int row = hb[mt] + fh * 64 + wcl;    // (2*ohl+fh)*64 + w
            bf16x8 vv = lds8[row * 8 + (ccq ^ ((wcl >> 1) & 7))];
            a[mt] = pad ? one8 : vv;
        }
        bf16x8 b2[4];
        if (ks < 16) {
            #pragma unroll
            for (int nt = 0; nt < 4; ++nt)
                b2[nt] = Btv[((ks + 2) * 16 + wv4 + nt) * 64 + lane];
        }
        // spread tile1 x-loads: 2/step for ks<16, 4/step for ks=16,17
        if (ks < 16) {
            #pragma unroll
            for (int u = 0; u < 2; ++u) {
                const int k = 2 * ks + u;          // 0..31
                v1[k] = *(const float2*)(xc + (k >> 3) * 64 + ((k & 7) << 12));
            }
        } else {
            #pragma unroll
            for (int u = 0; u < 4; ++u) {
                const int k = 32 + ((ks - 16) << 2) + u;   // 32..39
                v1[k] = *(const float2*)(xc + (k >> 3) * 64 + ((k & 7) << 12));
            }
        }
        #pragma unroll
        for (int mt = 0; mt < 4; ++mt)
            #pragma unroll
            for (int nt = 0; nt < 4; ++nt)
                acc0[mt][nt] = __builtin_amdgcn_mfma_f32_16x16x32_bf16(
                    a[mt], b0[nt], acc0[mt][nt], 0, 0, 0);
        #pragma unroll
        for (int nt = 0; nt < 4; ++nt) { b0[nt] = b1[nt]; b1[nt] = b2[nt]; }
    }

    // ---- finish-stage tile1 (loads landed under kloop0) ------------------
    #pragma unroll
    for (int hl = 0; hl < 5; ++hl) {
        bf16x8 ca, cb;
        #pragma unroll
        for (int k = 0; k < 8; ++k) {
            ca[k] = (__bf16)__expf(v1[hl * 8 + k].x);
            cb[k] = (__bf16)__expf(v1[hl * 8 + k].y);
        }
        bf16x8* dst = lds8 + 2560 + hl * 512 + w0 * 8 + c8p;
        dst[0] = ca;
        dst[8] = cb;
    }
    #pragma unroll
    for (int nt = 0; nt < 4; ++nt) {
        b0[nt] = Btv[(wv4 + nt) * 64 + lane];            // ks = 0
        b1[nt] = Btv[(16 + wv4 + nt) * 64 + lane];       // ks = 1
    }
    #pragma unroll
    for (int mt = 0; mt < 4; ++mt)
        #pragma unroll
        for (int nt = 0; nt < 4; ++nt) acc1[mt][nt] = (f32x4)(0.0f);

    __syncthreads();   // B1: buf1 staged

    // ============ kloop1: tile1 MFMA + spread epi(tile0) chunks ===========
    #pragma unroll
    for (int ks = 0; ks < 18; ++ks) {
        const int p  = ks >> 1;
        const int fh = (p * 11) >> 5;
        const int fw = p - fh * 3;
        const int ccq = ((ks & 1) << 2) + q;
        bf16x8 a[4];
        #pragma unroll
        for (int mt = 0; mt < 4; ++mt) {
            const int wc  = wo2[mt] + fw - 1;
            const int pad = wc < 0;
            const int wcl = pad ? 0 : wc;
            const int row = hb[mt] + fh * 64 + wcl;
            bf16x8 vv = lds8[2560 + row * 8 + (ccq ^ ((wcl >> 1) & 7))];
            a[mt] = pad ? one8 : vv;
        }
        bf16x8 b2[4];
        if (ks < 16) {
            #pragma unroll
            for (int nt = 0; nt < 4; ++nt)
                b2[nt] = Btv[((ks + 2) * 16 + wv4 + nt) * 64 + lane];
        }
        // spread epi(tile0): one f32x4 chunk (4 logf + 1 store) per step
        if (ks < 16) {
            const int emt = ks >> 2, ent = ks & 3;
            const int m    = emt * 16 + (q << 2);  // C/D: row = q*4 + reg
            const int ohl  = m >> 5;
            const int owi  = m & 31;
            const int orow = (oh0a + ohl) * 32 + owi;
            const int inst = wv * 64 + ent * 16 + t16;
            f32x4 r;
            #pragma unroll
            for (int j = 0; j < 4; ++j)
                r[j] = __logf(acc0[emt][ent][j]) - lK;
            *(f32x4*)(out + (((size_t)b * 256 + inst) * 1024 + orow)) = r;
        }
        #pragma unroll
        for (int mt = 0; mt < 4; ++mt)
            #pragma unroll
            for (int nt = 0; nt < 4; ++nt)
                acc1[mt][nt] = __builtin_amdgcn_mfma_f32_16x16x32_bf16(
                    a[mt], b0[nt], acc1[mt][nt], 0, 0, 0);
        #pragma unroll
        for (int nt = 0; nt < 4; ++nt) { b0[nt] = b1[nt]; b1[nt] = b2[nt]; }
    }

    // ---- epilogue tile1: y = log(S) - log(576) ---------------------------
    #pragma unroll
    for (int mt = 0; mt < 4; ++mt) {
        const int m   = mt * 16 + (q << 2);        // C/D: row = q*4 + reg
        const int ohl = m >> 5;
        const int owi = m & 31;
        const int orow = (oh0b + ohl) * 32 + owi;
        #pragma unroll
        for (int nt = 0; nt < 4; ++nt) {
            const int inst = wv * 64 + nt * 16 + t16;   // C/D: col = t16
            f32x4 r;
            #pragma unroll
            for (int j = 0; j < 4; ++j)
                r[j] = __logf(acc1[mt][nt][j]) - lK;
            *(f32x4*)(out + (((size_t)b * 256 + inst) * 1024 + orow)) = r;
        }
    }
}

extern "C" void kernel_launch(void* const* d_in, const int* in_sizes, int n_in,
                              void* d_out, int out_size, void* d_ws, size_t ws_size,
                              hipStream_t stream) {
    const float* x   = (const float*)d_in[0];   // (64,64,64,64) fp32
    const float* off = (const float*)d_in[1];   // (1,256,64,3,3) fp32
    float* out = (float*)d_out;                 // (64,256,32,32) fp32
    __bf16* Bt = (__bf16*)d_ws;                 // 294912 B

    mex_prep_b<<<64, 256, 0, stream>>>(off, Bt);
    mex_main<<<512, 256, 0, stream>>>(x, Bt, out);
}